// Round 3
// baseline (189.245 us; speedup 1.0000x reference)
//
#include <hip/hip_runtime.h>
#include <hip/hip_bf16.h>

#define B_NUM 2
#define T_SEQ 2048
#define C_DIM 1024
#define H_NUM 16
#define HD    64
#define M_TOT 4096
#define BH_N  32

typedef __attribute__((ext_vector_type(8))) short short8;   // 8 bf16
typedef __attribute__((ext_vector_type(4))) float floatx4;  // 4 fp32 acc

__device__ __forceinline__ short f2bf(float f) {
    unsigned u = __float_as_uint(f);
    u += 0x7FFFu + ((u >> 16) & 1u);
    return (short)(u >> 16);
}

__device__ __forceinline__ unsigned pk2bf(float a, float b) {
    float2 f2; f2.x = a; f2.y = b;
    __hip_bfloat162 h = __float22bfloat162_rn(f2);
    unsigned u; __builtin_memcpy(&u, &h, 4); return u;
}

// async global->LDS, 16B per lane; LDS dest = wave-uniform base + lane*16
__device__ __forceinline__ void gld16(const short* g, short* l) {
    __builtin_amdgcn_global_load_lds(
        (const __attribute__((address_space(1))) void*)g,
        (__attribute__((address_space(3))) void*)l, 16, 0, 0);
}

// ===========================================================================
// prep: x fp32->bf16 (blocks 0..2047) and W/Wp transpose (blocks 2048..3071).
// f32 LDS staging with col' = c ^ d XOR swizzle (2-way banks on both sides).
// ===========================================================================
__global__ __launch_bounds__(256) void prep_k(
    const float* __restrict__ x, const float* __restrict__ Wq,
    const float* __restrict__ Wk, const float* __restrict__ Wv,
    const float* __restrict__ Wp,
    short* __restrict__ xb, short* __restrict__ wt, short* __restrict__ wpt) {
    const int bid = blockIdx.x;
    const int tid = threadIdx.x;
    if (bid < 2048) {
        int idx = (bid * 256 + tid) * 8;
        float4 a = *(const float4*)(x + idx);
        float4 b = *(const float4*)(x + idx + 4);
        short8 o;
        o[0] = f2bf(a.x); o[1] = f2bf(a.y); o[2] = f2bf(a.z); o[3] = f2bf(a.w);
        o[4] = f2bf(b.x); o[5] = f2bf(b.y); o[6] = f2bf(b.z); o[7] = f2bf(b.w);
        *(short8*)(xb + idx) = o;
        return;
    }
    const int b2 = bid - 2048;
    const int ct = b2 & 15, y = b2 >> 4;
    __shared__ float shf[4096];                 // 64x64 f32, XOR-swizzled cols

    const float* src;
    size_t src_stride;
    int src_col0;
    short* dst;
    int dst_col0;
    if (y < 48) {
        const int which = y >> 4, h = y & 15;
        src = ((which == 0) ? Wq : (which == 1) ? Wk : Wv)
              + (size_t)h * C_DIM * HD + (size_t)(ct * 64) * HD;
        src_stride = HD;  src_col0 = 0;
        dst = wt + (size_t)((which * 16 + h) * 64) * C_DIM;
        dst_col0 = ct * 64;
    } else {
        const int nt = y - 48;
        src = Wp + (size_t)(ct * 64) * C_DIM;
        src_stride = C_DIM;  src_col0 = nt * 64;
        dst = wpt + (size_t)(nt * 64) * C_DIM;
        dst_col0 = ct * 64;
    }
    #pragma unroll
    for (int p = 0; p < 4; ++p) {
        int idx = tid + 256 * p;
        int c = idx >> 4, d4 = idx & 15;
        float4 v = *(const float4*)(src + (size_t)c * src_stride + src_col0 + d4 * 4);
        shf[(d4 * 4 + 0) * 64 + (c ^ (d4 * 4 + 0))] = v.x;
        shf[(d4 * 4 + 1) * 64 + (c ^ (d4 * 4 + 1))] = v.y;
        shf[(d4 * 4 + 2) * 64 + (c ^ (d4 * 4 + 2))] = v.z;
        shf[(d4 * 4 + 3) * 64 + (c ^ (d4 * 4 + 3))] = v.w;
    }
    __syncthreads();
    #pragma unroll
    for (int p = 0; p < 2; ++p) {
        int idx = tid + 256 * p;
        int d = idx >> 3, cc = idx & 7;
        const float* row = shf + d * 64;
        uint4 u;
        u.x = pk2bf(row[(cc * 8 + 0) ^ d], row[(cc * 8 + 1) ^ d]);
        u.y = pk2bf(row[(cc * 8 + 2) ^ d], row[(cc * 8 + 3) ^ d]);
        u.z = pk2bf(row[(cc * 8 + 4) ^ d], row[(cc * 8 + 5) ^ d]);
        u.w = pk2bf(row[(cc * 8 + 6) ^ d], row[(cc * 8 + 7) ^ d]);
        *(uint4*)(dst + (size_t)d * C_DIM + dst_col0 + cc * 8) = u;
    }
}

// ===========================================================================
// qkv: C[4096 x 3072] = xb * wt^T, 256x256 tiles (was 128x128).
// Halves L2/L3 staging traffic (393 -> 196 MB) and doubles MFMA per staged
// byte (64 MFMA : 24 ds_read_b128 per wave per K-step). Grid 192 = 16x12,
// one block/CU, XCD-bijective swizzle (24 wg/XCD = 2 A-panels x 12 N-tiles
// -> 1 MB A-panel L2-resident per XCD).
// ===========================================================================
__global__ __launch_bounds__(512, 2) void qkv_k(
    const short* __restrict__ xb, const short* __restrict__ wt,
    short* __restrict__ qb, short* __restrict__ kb, short* __restrict__ vtb) {
    const int swz = (blockIdx.x & 7) * 24 + (blockIdx.x >> 3);   // 192%8==0: bijective
    const int mt = swz / 12, ntg = swz % 12;
    const int m0 = mt * 256, n0 = ntg * 256;
    const int which = n0 >> 10;                  // 256 | 1024: no straddle
    const float sc = (which == 0) ? 0.125f * 1.4426950408889634f : 1.0f;

    __shared__ short smem[32768];                // 64 KiB
    short* As = smem;                            // [256][64] swizzled
    short* Bs = smem + 16384;                    // [256][64] swizzled

    const int tid = threadIdx.x;
    const int lane = tid & 63, w = tid >> 6;     // 8 waves
    const int wm = w & 1, wn = w >> 1;           // 2 (M) x 4 (N)
    const int hi = lane >> 4, llo = lane & 15;
    const int lrow = lane >> 3;
    const int lswz = ((lane & 7) ^ (lrow & 7)) * 8;
    const int fc0 = (hi ^ (llo & 7)) * 8;
    const int fc1 = ((hi + 4) ^ (llo & 7)) * 8;

    floatx4 acc[8][4];
    #pragma unroll
    for (int i = 0; i < 8; ++i)
        #pragma unroll
        for (int j = 0; j < 4; ++j)
            #pragma unroll
            for (int r = 0; r < 4; ++r) acc[i][j][r] = 0.0f;

    const size_t a_base = (size_t)(m0 + w * 32 + lrow) * C_DIM + lswz;
    const size_t b_base = (size_t)(n0 + w * 32 + lrow) * C_DIM + lswz;

    for (int kt = 0; kt < C_DIM / 64; ++kt) {
        const int c0 = kt * 64;
        __syncthreads();
        #pragma unroll
        for (int p = 0; p < 4; ++p) {
            gld16(xb + a_base + (size_t)p * 8 * C_DIM + c0, &As[(w * 32 + p * 8) * 64]);
            gld16(wt + b_base + (size_t)p * 8 * C_DIM + c0, &Bs[(w * 32 + p * 8) * 64]);
        }
        __syncthreads();

        // cache all 4 B-fragment pairs (32 VGPR), stream A-fragments
        short8 bf[4][2];
        #pragma unroll
        for (int ni = 0; ni < 4; ++ni) {
            const int row = wn * 64 + ni * 16 + llo;
            bf[ni][0] = *(const short8*)(&Bs[row * 64 + fc0]);
            bf[ni][1] = *(const short8*)(&Bs[row * 64 + fc1]);
        }
        #pragma unroll
        for (int mi = 0; mi < 8; ++mi) {
            const int row = wm * 128 + mi * 16 + llo;
            short8 a0 = *(const short8*)(&As[row * 64 + fc0]);
            short8 a1 = *(const short8*)(&As[row * 64 + fc1]);
            #pragma unroll
            for (int ni = 0; ni < 4; ++ni) {
                acc[mi][ni] = __builtin_amdgcn_mfma_f32_16x16x32_bf16(a0, bf[ni][0], acc[mi][ni], 0, 0, 0);
                acc[mi][ni] = __builtin_amdgcn_mfma_f32_16x16x32_bf16(a1, bf[ni][1], acc[mi][ni], 0, 0, 0);
            }
        }
    }

    const int bb = m0 >> 11;
    if (which < 2) {
        // q/k: out[(bb*16+h)*2048 + t][d], per-64-col chunk via LDS transpose
        short (*R)[76] = (short(*)[76])smem;     // 256x76 = 38.9 KB
        short* outp = (which == 0) ? qb : kb;
        #pragma unroll
        for (int c = 0; c < 4; ++c) {
            __syncthreads();
            if (wn == c) {
                #pragma unroll
                for (int mi = 0; mi < 8; ++mi)
                    #pragma unroll
                    for (int ni = 0; ni < 4; ++ni)
                        #pragma unroll
                        for (int r = 0; r < 4; ++r)
                            R[wm * 128 + mi * 16 + hi * 4 + r][ni * 16 + llo] =
                                f2bf(acc[mi][ni][r] * sc);
            }
            __syncthreads();
            const int h = ((n0 + c * 64) >> 6) & 15;
            #pragma unroll
            for (int p = 0; p < 4; ++p) {
                int idx = tid + 512 * p;
                int r = idx >> 3, cc = idx & 7;
                short8 vv = *(const short8*)(&R[r][cc * 8]);
                int t = (m0 + r) & 2047;
                *(short8*)(outp + ((size_t)(bb * H_NUM + h) * T_SEQ + t) * HD + cc * 8) = vv;
            }
        }
    } else {
        // v: vtb[(bb*16+h)*64 + d][t], per-64-col chunk via LDS transpose
        short (*R2)[268] = (short(*)[268])smem;  // 64x268 = 34.3 KB
        #pragma unroll
        for (int c = 0; c < 4; ++c) {
            __syncthreads();
            if (wn == c) {
                #pragma unroll
                for (int mi = 0; mi < 8; ++mi)
                    #pragma unroll
                    for (int ni = 0; ni < 4; ++ni)
                        #pragma unroll
                        for (int r = 0; r < 4; ++r)
                            R2[ni * 16 + llo][wm * 128 + mi * 16 + hi * 4 + r] =
                                f2bf(acc[mi][ni][r]);
            }
            __syncthreads();
            const int h = ((n0 + c * 64) >> 6) & 15;
            #pragma unroll
            for (int p = 0; p < 4; ++p) {
                int idx = tid + 512 * p;
                int d = idx >> 5, cc = idx & 31;
                short8 vv = *(const short8*)(&R2[d][cc * 8]);
                *(short8*)(vtb + ((size_t)((bb * H_NUM + h) * HD + d)) * T_SEQ
                           + (m0 & 2047) + cc * 8) = vv;
            }
        }
    }
}

__global__ __launch_bounds__(512) void attn_k(
    const short* __restrict__ qb, const short* __restrict__ kb,
    const short* __restrict__ vtb, short* __restrict__ attb) {
    const int bh = blockIdx.x;
    const int y = blockIdx.y;
    const int qt = (y < 8) ? (15 - y) : (y - 8);
    const int b = bh >> 4, h = bh & 15;
    const short* K  = kb  + (size_t)bh * T_SEQ * HD;
    const short* Vt = vtb + (size_t)bh * HD * T_SEQ;

    __shared__ short Ks[2][4096];
    __shared__ short Vs[2][4096];
    __shared__ short Ps[128][76];

    const int tid = threadIdx.x;
    const int lane = tid & 63, w = tid >> 6;
    const int hi = lane >> 4, llo = lane & 15;
    const int lrow = lane >> 3;
    const int lswz = ((lane & 7) ^ (lrow & 7)) * 8;
    const int fc0 = (hi ^ (llo & 7)) * 8;
    const int fc1 = ((hi + 4) ^ (llo & 7)) * 8;
    const int kmax = 2 * qt + 1;

    short8 qf[2];
    const int qcol0 = qt * 128 + w * 16;
    #pragma unroll
    for (int kh = 0; kh < 2; ++kh)
        qf[kh] = *(const short8*)(qb +
            ((size_t)bh * T_SEQ + qcol0 + llo) * HD + kh * 32 + hi * 8);

    short8 av4;
    #pragma unroll
    for (int j = 0; j < 8; ++j) av4[j] = (llo == 0) ? (short)0x3F80 : (short)0;

    gld16(K + (size_t)(w * 8 + lrow) * HD + lswz, &Ks[0][(w * 8) * 64]);
    gld16(Vt + (size_t)(w * 8 + lrow) * T_SEQ + lswz, &Vs[0][(w * 8) * 64]);

    floatx4 Oa[5];
    #pragma unroll
    for (int n = 0; n < 5; ++n)
        #pragma unroll
        for (int r = 0; r < 4; ++r) Oa[n][r] = 0.0f;

    for (int kt = 0; kt <= kmax; ++kt) {
        __syncthreads();
        const int buf = kt & 1;

        if (kt + 1 <= kmax) {
            const int s0 = (kt + 1) * 64;
            const int nb = buf ^ 1;
            gld16(K + ((size_t)s0 + w * 8 + lrow) * HD + lswz, &Ks[nb][(w * 8) * 64]);
            gld16(Vt + (size_t)(w * 8 + lrow) * T_SEQ + s0 + lswz, &Vs[nb][(w * 8) * 64]);
        }

        short8 ak[4][2];
        #pragma unroll
        for (int nt = 0; nt < 4; ++nt) {
            const int row = nt * 16 + llo;
            ak[nt][0] = *(const short8*)(&Ks[buf][row * 64 + fc0]);
            ak[nt][1] = *(const short8*)(&Ks[buf][row * 64 + fc1]);
        }
        floatx4 sf[4];
        #pragma unroll
        for (int nt = 0; nt < 4; ++nt)
            #pragma unroll
            for (int r = 0; r < 4; ++r) sf[nt][r] = 0.0f;
        __builtin_amdgcn_s_setprio(1);
        #pragma unroll
        for (int nt = 0; nt < 4; ++nt)
            #pragma unroll
            for (int kh = 0; kh < 2; ++kh)
                sf[nt] = __builtin_amdgcn_mfma_f32_16x16x32_bf16(
                    ak[nt][kh], qf[kh], sf[nt], 0, 0, 0);
        __builtin_amdgcn_s_setprio(0);

        const int sbase = kt * 64;
        if (sbase + 63 > qcol0) {
            const int qlane = qcol0 + llo;
            #pragma unroll
            for (int nt = 0; nt < 4; ++nt)
                #pragma unroll
                for (int r = 0; r < 4; ++r)
                    if (sbase + nt * 16 + hi * 4 + r > qlane) sf[nt][r] = -3.0e38f;
        }

        #pragma unroll
        for (int nt = 0; nt < 4; ++nt) {
            float p0 = __builtin_amdgcn_exp2f(sf[nt][0]);
            float p1 = __builtin_amdgcn_exp2f(sf[nt][1]);
            float p2 = __builtin_amdgcn_exp2f(sf[nt][2]);
            float p3 = __builtin_amdgcn_exp2f(sf[nt][3]);
            uint2 u; u.x = pk2bf(p0, p1); u.y = pk2bf(p2, p3);
            *(uint2*)(&Ps[w * 16 + llo][nt * 16 + hi * 4]) = u;
        }

        short8 av[5][2];
        #pragma unroll
        for (int nt2 = 0; nt2 < 4; ++nt2) {
            const int row = nt2 * 16 + llo;
            av[nt2][0] = *(const short8*)(&Vs[buf][row * 64 + fc0]);
            av[nt2][1] = *(const short8*)(&Vs[buf][row * 64 + fc1]);
        }
        av[4][0] = av4;
        av[4][1] = av4;
        short8 bpf[2];
        #pragma unroll
        for (int kh = 0; kh < 2; ++kh)
            bpf[kh] = *(const short8*)(&Ps[w * 16 + llo][kh * 32 + hi * 8]);
        __builtin_amdgcn_s_setprio(1);
        #pragma unroll
        for (int nt2 = 0; nt2 < 5; ++nt2)
            #pragma unroll
            for (int kh = 0; kh < 2; ++kh)
                Oa[nt2] = __builtin_amdgcn_mfma_f32_16x16x32_bf16(
                    av[nt2][kh], bpf[kh], Oa[nt2], 0, 0, 0);
        __builtin_amdgcn_s_setprio(0);
    }

    {
        float lb = __shfl(Oa[4][0], llo);
        float inv = 1.0f / lb;
        #pragma unroll
        for (int nt2 = 0; nt2 < 4; ++nt2) {
            uint2 u;
            u.x = pk2bf(Oa[nt2][0] * inv, Oa[nt2][1] * inv);
            u.y = pk2bf(Oa[nt2][2] * inv, Oa[nt2][3] * inv);
            *(uint2*)(&Ps[w * 16 + llo][nt2 * 16 + hi * 4]) = u;
        }
    }
    __syncthreads();
    #pragma unroll
    for (int p = 0; p < 2; ++p) {
        int idx = tid + 512 * p;
        int r = idx >> 3, cc = idx & 7;
        short8 vv = *(const short8*)(&Ps[r][cc * 8]);
        *(short8*)(attb + ((size_t)(b * T_SEQ + qt * 128 + r)) * C_DIM + h * HD + cc * 8) = vv;
    }
}

__global__ __launch_bounds__(256) void proj_k(
    const short* __restrict__ attb, const short* __restrict__ wpt,
    const float* __restrict__ bp, float* __restrict__ out) {
    const int mt = blockIdx.x, ntg = blockIdx.y;
    const int m0 = mt * 128, n0 = ntg * 128;

    __shared__ short smem[16384];
    short* As = smem;
    short* Bs = smem + 8192;

    const int tid = threadIdx.x;
    const int lane = tid & 63, w = tid >> 6;
    const int wm = w & 1, wn = w >> 1;
    const int hi = lane >> 4, llo = lane & 15;
    const int lrow = lane >> 3;
    const int lswz = ((lane & 7) ^ (lrow & 7)) * 8;
    const int fc0 = (hi ^ (llo & 7)) * 8;
    const int fc1 = ((hi + 4) ^ (llo & 7)) * 8;

    floatx4 acc[4][4];
    #pragma unroll
    for (int i = 0; i < 4; ++i)
        #pragma unroll
        for (int j = 0; j < 4; ++j)
            #pragma unroll
            for (int r = 0; r < 4; ++r) acc[i][j][r] = 0.0f;

    const size_t a_base = (size_t)(m0 + w * 32 + lrow) * C_DIM + lswz;
    const size_t b_base = (size_t)(n0 + w * 32 + lrow) * C_DIM + lswz;

    for (int kt = 0; kt < C_DIM / 64; ++kt) {
        const int c0 = kt * 64;
        __syncthreads();
        #pragma unroll
        for (int p = 0; p < 4; ++p) {
            gld16(attb + a_base + (size_t)p * 8 * C_DIM + c0, &As[(w * 32 + p * 8) * 64]);
            gld16(wpt  + b_base + (size_t)p * 8 * C_DIM + c0, &Bs[(w * 32 + p * 8) * 64]);
        }
        __syncthreads();

        short8 af[4][2];
        #pragma unroll
        for (int mi = 0; mi < 4; ++mi) {
            const int row = wm * 64 + mi * 16 + llo;
            af[mi][0] = *(const short8*)(&As[row * 64 + fc0]);
            af[mi][1] = *(const short8*)(&As[row * 64 + fc1]);
        }
        #pragma unroll
        for (int ni = 0; ni < 4; ++ni) {
            const int row = wn * 64 + ni * 16 + llo;
            short8 b0 = *(const short8*)(&Bs[row * 64 + fc0]);
            short8 b1 = *(const short8*)(&Bs[row * 64 + fc1]);
            #pragma unroll
            for (int mi = 0; mi < 4; ++mi) {
                acc[mi][ni] = __builtin_amdgcn_mfma_f32_16x16x32_bf16(af[mi][0], b0, acc[mi][ni], 0, 0, 0);
                acc[mi][ni] = __builtin_amdgcn_mfma_f32_16x16x32_bf16(af[mi][1], b1, acc[mi][ni], 0, 0, 0);
            }
        }
    }

    #pragma unroll
    for (int ni = 0; ni < 4; ++ni) {
        const int n = n0 + wn * 64 + ni * 16 + llo;
        const float bias = bp[n];
        #pragma unroll
        for (int mi = 0; mi < 4; ++mi)
            #pragma unroll
            for (int r = 0; r < 4; ++r) {
                int m = m0 + wm * 64 + mi * 16 + hi * 4 + r;
                out[(size_t)m * C_DIM + n] = acc[mi][ni][r] + bias;
            }
    }
}

// ---------------------------------------------------------------------------
extern "C" void kernel_launch(void* const* d_in, const int* in_sizes, int n_in,
                              void* d_out, int out_size, void* d_ws, size_t ws_size,
                              hipStream_t stream) {
    const float* x  = (const float*)d_in[0];
    const float* Wq = (const float*)d_in[1];
    const float* Wk = (const float*)d_in[2];
    const float* Wv = (const float*)d_in[3];
    const float* Wp = (const float*)d_in[4];
    const float* bp = (const float*)d_in[5];
    float* out = (float*)d_out;

    short* xb   = (short*)d_ws;
    short* wt   = xb  + (size_t)M_TOT * C_DIM;
    short* wpt  = wt  + (size_t)3 * H_NUM * HD * C_DIM;
    short* qb   = wpt + (size_t)C_DIM * C_DIM;
    short* kb   = qb  + (size_t)M_TOT * C_DIM;
    short* vtb  = kb  + (size_t)M_TOT * C_DIM;
    short* attb = vtb + (size_t)M_TOT * C_DIM;

    prep_k<<<dim3(3072), 256, 0, stream>>>(x, Wq, Wk, Wv, Wp, xb, wt, wpt);
    qkv_k <<<dim3(192), 512, 0, stream>>>(xb, wt, qb, kb, vtb);
    attn_k<<<dim3(BH_N, T_SEQ / 128), 512, 0, stream>>>(qb, kb, vtb, attb);
    proj_k<<<dim3(M_TOT / 128, C_DIM / 128), 256, 0, stream>>>(attb, wpt, bp, out);
}

// Round 4
// 167.710 us; speedup vs baseline: 1.1284x; 1.1284x over previous
//
#include <hip/hip_runtime.h>
#include <hip/hip_bf16.h>

#define B_NUM 2
#define T_SEQ 2048
#define C_DIM 1024
#define H_NUM 16
#define HD    64
#define M_TOT 4096
#define BH_N  32

typedef __attribute__((ext_vector_type(8))) short short8;   // 8 bf16
typedef __attribute__((ext_vector_type(4))) float floatx4;  // 4 fp32 acc

__device__ __forceinline__ short f2bf(float f) {
    unsigned u = __float_as_uint(f);
    u += 0x7FFFu + ((u >> 16) & 1u);
    return (short)(u >> 16);
}

__device__ __forceinline__ unsigned pk2bf(float a, float b) {
    float2 f2; f2.x = a; f2.y = b;
    __hip_bfloat162 h = __float22bfloat162_rn(f2);
    unsigned u; __builtin_memcpy(&u, &h, 4); return u;
}

// async global->LDS, 16B per lane; LDS dest = wave-uniform base + lane*16
__device__ __forceinline__ void gld16(const short* g, short* l) {
    __builtin_amdgcn_global_load_lds(
        (const __attribute__((address_space(1))) void*)g,
        (__attribute__((address_space(3))) void*)l, 16, 0, 0);
}

// ===========================================================================
// prep: x fp32->bf16 (blocks 0..2047) and W/Wp transpose (blocks 2048..3071).
// f32 LDS staging with col' = c ^ d XOR swizzle (2-way banks on both sides).
// ===========================================================================
__global__ __launch_bounds__(256) void prep_k(
    const float* __restrict__ x, const float* __restrict__ Wq,
    const float* __restrict__ Wk, const float* __restrict__ Wv,
    const float* __restrict__ Wp,
    short* __restrict__ xb, short* __restrict__ wt, short* __restrict__ wpt) {
    const int bid = blockIdx.x;
    const int tid = threadIdx.x;
    if (bid < 2048) {
        int idx = (bid * 256 + tid) * 8;
        float4 a = *(const float4*)(x + idx);
        float4 b = *(const float4*)(x + idx + 4);
        short8 o;
        o[0] = f2bf(a.x); o[1] = f2bf(a.y); o[2] = f2bf(a.z); o[3] = f2bf(a.w);
        o[4] = f2bf(b.x); o[5] = f2bf(b.y); o[6] = f2bf(b.z); o[7] = f2bf(b.w);
        *(short8*)(xb + idx) = o;
        return;
    }
    const int b2 = bid - 2048;
    const int ct = b2 & 15, y = b2 >> 4;
    __shared__ float shf[4096];                 // 64x64 f32, XOR-swizzled cols

    const float* src;
    size_t src_stride;
    int src_col0;
    short* dst;
    int dst_col0;
    if (y < 48) {
        const int which = y >> 4, h = y & 15;
        src = ((which == 0) ? Wq : (which == 1) ? Wk : Wv)
              + (size_t)h * C_DIM * HD + (size_t)(ct * 64) * HD;
        src_stride = HD;  src_col0 = 0;
        dst = wt + (size_t)((which * 16 + h) * 64) * C_DIM;
        dst_col0 = ct * 64;
    } else {
        const int nt = y - 48;
        src = Wp + (size_t)(ct * 64) * C_DIM;
        src_stride = C_DIM;  src_col0 = nt * 64;
        dst = wpt + (size_t)(nt * 64) * C_DIM;
        dst_col0 = ct * 64;
    }
    #pragma unroll
    for (int p = 0; p < 4; ++p) {
        int idx = tid + 256 * p;
        int c = idx >> 4, d4 = idx & 15;
        float4 v = *(const float4*)(src + (size_t)c * src_stride + src_col0 + d4 * 4);
        shf[(d4 * 4 + 0) * 64 + (c ^ (d4 * 4 + 0))] = v.x;
        shf[(d4 * 4 + 1) * 64 + (c ^ (d4 * 4 + 1))] = v.y;
        shf[(d4 * 4 + 2) * 64 + (c ^ (d4 * 4 + 2))] = v.z;
        shf[(d4 * 4 + 3) * 64 + (c ^ (d4 * 4 + 3))] = v.w;
    }
    __syncthreads();
    #pragma unroll
    for (int p = 0; p < 2; ++p) {
        int idx = tid + 256 * p;
        int d = idx >> 3, cc = idx & 7;
        const float* row = shf + d * 64;
        uint4 u;
        u.x = pk2bf(row[(cc * 8 + 0) ^ d], row[(cc * 8 + 1) ^ d]);
        u.y = pk2bf(row[(cc * 8 + 2) ^ d], row[(cc * 8 + 3) ^ d]);
        u.z = pk2bf(row[(cc * 8 + 4) ^ d], row[(cc * 8 + 5) ^ d]);
        u.w = pk2bf(row[(cc * 8 + 6) ^ d], row[(cc * 8 + 7) ^ d]);
        *(uint4*)(dst + (size_t)d * C_DIM + dst_col0 + cc * 8) = u;
    }
}

// ===========================================================================
// qkv: C[4096 x 3072] = xb * wt^T. 256x192 tiles -> 16x16 = 256 blocks =
// exactly 1/CU (round-3's 192-block 256^2 left 25% of CUs idle).
// T3-minimum double-buffer: STAGE(t+1) issued BEFORE compute(t), ONE
// vmcnt(0)+barrier per K-step (was: barrier-stage-barrier fully serial).
// LDS 112 KiB dynamic (2 x (A 32K + B 24K)) via hipFuncSetAttribute.
// ===========================================================================
__global__ __launch_bounds__(512, 1) void qkv_k(
    const short* __restrict__ xb, const short* __restrict__ wt,
    short* __restrict__ qb, short* __restrict__ kb, short* __restrict__ vtb) {
    extern __shared__ short smem[];              // 57344 shorts = 112 KiB
    // A0 [0,16384)  A1 [16384,32768)  B0 [32768,45056)  B1 [45056,57344)

    const int swz = (blockIdx.x & 7) * 32 + (blockIdx.x >> 3);  // 256%8==0: bijective
    const int mt = swz >> 4, ntg = swz & 15;
    const int m0 = mt * 256, n0 = ntg * 192;

    const int tid = threadIdx.x;
    const int lane = tid & 63, w = tid >> 6;     // 8 waves
    const int wm = w & 1, wn = w >> 1;           // 2 (M) x 4 (N); wave tile 128x48
    const int hi = lane >> 4, llo = lane & 15;
    const int lrow = lane >> 3;
    const int lswz = ((lane & 7) ^ (lrow & 7)) * 8;
    const int fc0 = (hi ^ (llo & 7)) * 8;
    const int fc1 = ((hi + 4) ^ (llo & 7)) * 8;

    floatx4 acc[8][3];
    #pragma unroll
    for (int i = 0; i < 8; ++i)
        #pragma unroll
        for (int j = 0; j < 3; ++j)
            #pragma unroll
            for (int r = 0; r < 4; ++r) acc[i][j][r] = 0.0f;

    const size_t a_base = (size_t)(m0 + w * 32 + lrow) * C_DIM + lswz;
    const size_t b_base = (size_t)(n0 + w * 24 + lrow) * C_DIM + lswz;

    auto STAGE = [&](int bsel, int kt) {
        const int c0 = kt * 64;
        short* Ad = smem + bsel * 16384;
        short* Bd = smem + 32768 + bsel * 12288;
        #pragma unroll
        for (int p = 0; p < 4; ++p)
            gld16(xb + a_base + (size_t)p * 8 * C_DIM + c0, &Ad[(w * 32 + p * 8) * 64]);
        #pragma unroll
        for (int p = 0; p < 3; ++p)
            gld16(wt + b_base + (size_t)p * 8 * C_DIM + c0, &Bd[(w * 24 + p * 8) * 64]);
    };

    STAGE(0, 0);
    __syncthreads();                             // prologue drain

    for (int kt = 0; kt < 16; ++kt) {
        const int cur = kt & 1;
        if (kt < 15) STAGE(cur ^ 1, kt + 1);     // next-tile loads in flight

        const short* As = smem + cur * 16384;
        const short* Bs = smem + 32768 + cur * 12288;

        short8 bf[3][2];
        #pragma unroll
        for (int ni = 0; ni < 3; ++ni) {
            const int row = wn * 48 + ni * 16 + llo;
            bf[ni][0] = *(const short8*)(&Bs[row * 64 + fc0]);
            bf[ni][1] = *(const short8*)(&Bs[row * 64 + fc1]);
        }
        #pragma unroll
        for (int mi = 0; mi < 8; ++mi) {
            const int row = wm * 128 + mi * 16 + llo;
            short8 a0 = *(const short8*)(&As[row * 64 + fc0]);
            short8 a1 = *(const short8*)(&As[row * 64 + fc1]);
            #pragma unroll
            for (int ni = 0; ni < 3; ++ni) {
                acc[mi][ni] = __builtin_amdgcn_mfma_f32_16x16x32_bf16(a0, bf[ni][0], acc[mi][ni], 0, 0, 0);
                acc[mi][ni] = __builtin_amdgcn_mfma_f32_16x16x32_bf16(a1, bf[ni][1], acc[mi][ni], 0, 0, 0);
            }
        }
        __syncthreads();                         // one barrier per K-step
    }

    // epilogue: three 64-col chunks, each uniform in {q,k,v} and head h
    const int bb = m0 >> 11;
    #pragma unroll
    for (int c = 0; c < 3; ++c) {
        const int nch = n0 + c * 64;
        const int which = nch >> 10;
        const int h = (nch >> 6) & 15;
        __syncthreads();
        if (which == 2) {
            short (*R2)[268] = (short(*)[268])smem;    // 64 x 268 = 34.3 KB
            #pragma unroll
            for (int ni = 0; ni < 3; ++ni) {
                const int gcol = wn * 48 + ni * 16;
                if ((gcol >> 6) == c) {
                    #pragma unroll
                    for (int mi = 0; mi < 8; ++mi)
                        #pragma unroll
                        for (int r = 0; r < 4; ++r)
                            R2[(gcol & 63) + llo][wm * 128 + mi * 16 + hi * 4 + r] =
                                f2bf(acc[mi][ni][r]);
                }
            }
            __syncthreads();
            #pragma unroll
            for (int p = 0; p < 4; ++p) {
                int idx = tid + 512 * p;
                int d = idx >> 5, cc = idx & 31;
                short8 vv = *(const short8*)(&R2[d][cc * 8]);
                *(short8*)(vtb + ((size_t)((bb * H_NUM + h) * HD + d)) * T_SEQ
                           + (m0 & 2047) + cc * 8) = vv;
            }
        } else {
            short (*R)[76] = (short(*)[76])smem;       // 256 x 76 = 38.9 KB
            const float scl = (which == 0) ? 0.125f * 1.4426950408889634f : 1.0f;
            short* outp = (which == 0) ? qb : kb;
            #pragma unroll
            for (int ni = 0; ni < 3; ++ni) {
                const int gcol = wn * 48 + ni * 16;
                if ((gcol >> 6) == c) {
                    #pragma unroll
                    for (int mi = 0; mi < 8; ++mi)
                        #pragma unroll
                        for (int r = 0; r < 4; ++r)
                            R[wm * 128 + mi * 16 + hi * 4 + r][(gcol & 63) + llo] =
                                f2bf(acc[mi][ni][r] * scl);
                }
            }
            __syncthreads();
            #pragma unroll
            for (int p = 0; p < 4; ++p) {
                int idx = tid + 512 * p;
                int rr = idx >> 3, cc = idx & 7;
                short8 vv = *(const short8*)(&R[rr][cc * 8]);
                int t = (m0 + rr) & 2047;
                *(short8*)(outp + ((size_t)(bb * H_NUM + h) * T_SEQ + t) * HD + cc * 8) = vv;
            }
        }
    }
}

__global__ __launch_bounds__(512) void attn_k(
    const short* __restrict__ qb, const short* __restrict__ kb,
    const short* __restrict__ vtb, short* __restrict__ attb) {
    const int bh = blockIdx.x;
    const int y = blockIdx.y;
    const int qt = (y < 8) ? (15 - y) : (y - 8);
    const int b = bh >> 4, h = bh & 15;
    const short* K  = kb  + (size_t)bh * T_SEQ * HD;
    const short* Vt = vtb + (size_t)bh * HD * T_SEQ;

    __shared__ short Ks[2][4096];
    __shared__ short Vs[2][4096];
    __shared__ short Ps[128][76];

    const int tid = threadIdx.x;
    const int lane = tid & 63, w = tid >> 6;
    const int hi = lane >> 4, llo = lane & 15;
    const int lrow = lane >> 3;
    const int lswz = ((lane & 7) ^ (lrow & 7)) * 8;
    const int fc0 = (hi ^ (llo & 7)) * 8;
    const int fc1 = ((hi + 4) ^ (llo & 7)) * 8;
    const int kmax = 2 * qt + 1;

    short8 qf[2];
    const int qcol0 = qt * 128 + w * 16;
    #pragma unroll
    for (int kh = 0; kh < 2; ++kh)
        qf[kh] = *(const short8*)(qb +
            ((size_t)bh * T_SEQ + qcol0 + llo) * HD + kh * 32 + hi * 8);

    short8 av4;
    #pragma unroll
    for (int j = 0; j < 8; ++j) av4[j] = (llo == 0) ? (short)0x3F80 : (short)0;

    gld16(K + (size_t)(w * 8 + lrow) * HD + lswz, &Ks[0][(w * 8) * 64]);
    gld16(Vt + (size_t)(w * 8 + lrow) * T_SEQ + lswz, &Vs[0][(w * 8) * 64]);

    floatx4 Oa[5];
    #pragma unroll
    for (int n = 0; n < 5; ++n)
        #pragma unroll
        for (int r = 0; r < 4; ++r) Oa[n][r] = 0.0f;

    for (int kt = 0; kt <= kmax; ++kt) {
        __syncthreads();
        const int buf = kt & 1;

        if (kt + 1 <= kmax) {
            const int s0 = (kt + 1) * 64;
            const int nb = buf ^ 1;
            gld16(K + ((size_t)s0 + w * 8 + lrow) * HD + lswz, &Ks[nb][(w * 8) * 64]);
            gld16(Vt + (size_t)(w * 8 + lrow) * T_SEQ + s0 + lswz, &Vs[nb][(w * 8) * 64]);
        }

        short8 ak[4][2];
        #pragma unroll
        for (int nt = 0; nt < 4; ++nt) {
            const int row = nt * 16 + llo;
            ak[nt][0] = *(const short8*)(&Ks[buf][row * 64 + fc0]);
            ak[nt][1] = *(const short8*)(&Ks[buf][row * 64 + fc1]);
        }
        floatx4 sf[4];
        #pragma unroll
        for (int nt = 0; nt < 4; ++nt)
            #pragma unroll
            for (int r = 0; r < 4; ++r) sf[nt][r] = 0.0f;
        __builtin_amdgcn_s_setprio(1);
        #pragma unroll
        for (int nt = 0; nt < 4; ++nt)
            #pragma unroll
            for (int kh = 0; kh < 2; ++kh)
                sf[nt] = __builtin_amdgcn_mfma_f32_16x16x32_bf16(
                    ak[nt][kh], qf[kh], sf[nt], 0, 0, 0);
        __builtin_amdgcn_s_setprio(0);

        const int sbase = kt * 64;
        if (sbase + 63 > qcol0) {
            const int qlane = qcol0 + llo;
            #pragma unroll
            for (int nt = 0; nt < 4; ++nt)
                #pragma unroll
                for (int r = 0; r < 4; ++r)
                    if (sbase + nt * 16 + hi * 4 + r > qlane) sf[nt][r] = -3.0e38f;
        }

        #pragma unroll
        for (int nt = 0; nt < 4; ++nt) {
            float p0 = __builtin_amdgcn_exp2f(sf[nt][0]);
            float p1 = __builtin_amdgcn_exp2f(sf[nt][1]);
            float p2 = __builtin_amdgcn_exp2f(sf[nt][2]);
            float p3 = __builtin_amdgcn_exp2f(sf[nt][3]);
            uint2 u; u.x = pk2bf(p0, p1); u.y = pk2bf(p2, p3);
            *(uint2*)(&Ps[w * 16 + llo][nt * 16 + hi * 4]) = u;
        }

        short8 av[5][2];
        #pragma unroll
        for (int nt2 = 0; nt2 < 4; ++nt2) {
            const int row = nt2 * 16 + llo;
            av[nt2][0] = *(const short8*)(&Vs[buf][row * 64 + fc0]);
            av[nt2][1] = *(const short8*)(&Vs[buf][row * 64 + fc1]);
        }
        av[4][0] = av4;
        av[4][1] = av4;
        short8 bpf[2];
        #pragma unroll
        for (int kh = 0; kh < 2; ++kh)
            bpf[kh] = *(const short8*)(&Ps[w * 16 + llo][kh * 32 + hi * 8]);
        __builtin_amdgcn_s_setprio(1);
        #pragma unroll
        for (int nt2 = 0; nt2 < 5; ++nt2)
            #pragma unroll
            for (int kh = 0; kh < 2; ++kh)
                Oa[nt2] = __builtin_amdgcn_mfma_f32_16x16x32_bf16(
                    av[nt2][kh], bpf[kh], Oa[nt2], 0, 0, 0);
        __builtin_amdgcn_s_setprio(0);
    }

    {
        float lb = __shfl(Oa[4][0], llo);
        float inv = 1.0f / lb;
        #pragma unroll
        for (int nt2 = 0; nt2 < 4; ++nt2) {
            uint2 u;
            u.x = pk2bf(Oa[nt2][0] * inv, Oa[nt2][1] * inv);
            u.y = pk2bf(Oa[nt2][2] * inv, Oa[nt2][3] * inv);
            *(uint2*)(&Ps[w * 16 + llo][nt2 * 16 + hi * 4]) = u;
        }
    }
    __syncthreads();
    #pragma unroll
    for (int p = 0; p < 2; ++p) {
        int idx = tid + 512 * p;
        int r = idx >> 3, cc = idx & 7;
        short8 vv = *(const short8*)(&Ps[r][cc * 8]);
        *(short8*)(attb + ((size_t)(b * T_SEQ + qt * 128 + r)) * C_DIM + h * HD + cc * 8) = vv;
    }
}

// ===========================================================================
// proj: 128x128 tiles, 256 blocks; + T3-minimum double-buffer (64 KB static):
// recovers the within-block stage/compute overlap lost when the grid went
// to 1 block/CU in round 2.
// ===========================================================================
__global__ __launch_bounds__(256) void proj_k(
    const short* __restrict__ attb, const short* __restrict__ wpt,
    const float* __restrict__ bp, float* __restrict__ out) {
    const int mt = blockIdx.x, ntg = blockIdx.y;
    const int m0 = mt * 128, n0 = ntg * 128;

    __shared__ short smem[32768];                // A0 A1 B0 B1, 8192 shorts each

    const int tid = threadIdx.x;
    const int lane = tid & 63, w = tid >> 6;
    const int wm = w & 1, wn = w >> 1;
    const int hi = lane >> 4, llo = lane & 15;
    const int lrow = lane >> 3;
    const int lswz = ((lane & 7) ^ (lrow & 7)) * 8;
    const int fc0 = (hi ^ (llo & 7)) * 8;
    const int fc1 = ((hi + 4) ^ (llo & 7)) * 8;

    floatx4 acc[4][4];
    #pragma unroll
    for (int i = 0; i < 4; ++i)
        #pragma unroll
        for (int j = 0; j < 4; ++j)
            #pragma unroll
            for (int r = 0; r < 4; ++r) acc[i][j][r] = 0.0f;

    const size_t a_base = (size_t)(m0 + w * 32 + lrow) * C_DIM + lswz;
    const size_t b_base = (size_t)(n0 + w * 32 + lrow) * C_DIM + lswz;

    auto STAGE = [&](int bsel, int kt) {
        const int c0 = kt * 64;
        short* Ad = smem + bsel * 8192;
        short* Bd = smem + 16384 + bsel * 8192;
        #pragma unroll
        for (int p = 0; p < 4; ++p) {
            gld16(attb + a_base + (size_t)p * 8 * C_DIM + c0, &Ad[(w * 32 + p * 8) * 64]);
            gld16(wpt  + b_base + (size_t)p * 8 * C_DIM + c0, &Bd[(w * 32 + p * 8) * 64]);
        }
    };

    STAGE(0, 0);
    __syncthreads();

    for (int kt = 0; kt < 16; ++kt) {
        const int cur = kt & 1;
        if (kt < 15) STAGE(cur ^ 1, kt + 1);

        const short* As = smem + cur * 8192;
        const short* Bs = smem + 16384 + cur * 8192;

        short8 af[4][2];
        #pragma unroll
        for (int mi = 0; mi < 4; ++mi) {
            const int row = wm * 64 + mi * 16 + llo;
            af[mi][0] = *(const short8*)(&As[row * 64 + fc0]);
            af[mi][1] = *(const short8*)(&As[row * 64 + fc1]);
        }
        #pragma unroll
        for (int ni = 0; ni < 4; ++ni) {
            const int row = wn * 64 + ni * 16 + llo;
            short8 b0 = *(const short8*)(&Bs[row * 64 + fc0]);
            short8 b1 = *(const short8*)(&Bs[row * 64 + fc1]);
            #pragma unroll
            for (int mi = 0; mi < 4; ++mi) {
                acc[mi][ni] = __builtin_amdgcn_mfma_f32_16x16x32_bf16(af[mi][0], b0, acc[mi][ni], 0, 0, 0);
                acc[mi][ni] = __builtin_amdgcn_mfma_f32_16x16x32_bf16(af[mi][1], b1, acc[mi][ni], 0, 0, 0);
            }
        }
        __syncthreads();
    }

    #pragma unroll
    for (int ni = 0; ni < 4; ++ni) {
        const int n = n0 + wn * 64 + ni * 16 + llo;
        const float bias = bp[n];
        #pragma unroll
        for (int mi = 0; mi < 4; ++mi)
            #pragma unroll
            for (int r = 0; r < 4; ++r) {
                int m = m0 + wm * 64 + mi * 16 + hi * 4 + r;
                out[(size_t)m * C_DIM + n] = acc[mi][ni][r] + bias;
            }
    }
}

// ---------------------------------------------------------------------------
extern "C" void kernel_launch(void* const* d_in, const int* in_sizes, int n_in,
                              void* d_out, int out_size, void* d_ws, size_t ws_size,
                              hipStream_t stream) {
    const float* x  = (const float*)d_in[0];
    const float* Wq = (const float*)d_in[1];
    const float* Wk = (const float*)d_in[2];
    const float* Wv = (const float*)d_in[3];
    const float* Wp = (const float*)d_in[4];
    const float* bp = (const float*)d_in[5];
    float* out = (float*)d_out;

    short* xb   = (short*)d_ws;
    short* wt   = xb  + (size_t)M_TOT * C_DIM;
    short* wpt  = wt  + (size_t)3 * H_NUM * HD * C_DIM;
    short* qb   = wpt + (size_t)C_DIM * C_DIM;
    short* kb   = qb  + (size_t)M_TOT * C_DIM;
    short* vtb  = kb  + (size_t)M_TOT * C_DIM;
    short* attb = vtb + (size_t)M_TOT * C_DIM;

    static bool attr_done = false;
    if (!attr_done) {
        (void)hipFuncSetAttribute((const void*)qkv_k,
                                  hipFuncAttributeMaxDynamicSharedMemorySize,
                                  114688);
        attr_done = true;
    }

    prep_k<<<dim3(3072), 256, 0, stream>>>(x, Wq, Wk, Wv, Wp, xb, wt, wpt);
    qkv_k <<<dim3(256), 512, 114688, stream>>>(xb, wt, qb, kb, vtb);
    attn_k<<<dim3(BH_N, T_SEQ / 128), 512, 0, stream>>>(qb, kb, vtb, attb);
    proj_k<<<dim3(M_TOT / 128, C_DIM / 128), 256, 0, stream>>>(attb, wpt, bp, out);
}